// Round 5
// baseline (424.071 us; speedup 1.0000x reference)
//
#include <hip/hip_runtime.h>

// CRF Viterbi decode (B=512, T=512, S=64).
// R4: 8 waves/block, one batch/block. fv lives in REGISTERS lane-wise in
// every wave (lane n = fv[n]). Per step: wave w gathers its 8-prev slice
// with v_readlane from its own fv, forms scores, reduces (max3 tree +
// first-index equality scan), publishes {val,idx} via one ds_write_b64 into
// an i&1 double-buffered array, ONE barrier, then ALL waves redundantly
// merge the 8 partials (ordered scan -> exact jnp first-argmax) and compute
// the new fv in-register. Masks + emissions prefetched depth-4 (never on
// the chain). Backpointers packed 4 tags/dword in LDS; backtrace = wave 0
// readlane chain (validated bit-exact in R1-R3).
// Output: out[0..B) = path_score, out[B + b*(T-1) + t] = (float)tag.

constexpr int Bz = 512;
constexpr int Tz = 512;
constexpr int Sz = 64;
constexpr float NEGINF = -10000.0f;

__device__ __forceinline__ float rlf(float x, int lane) {
    return __int_as_float(__builtin_amdgcn_readlane(__float_as_int(x), lane));
}

__global__ __launch_bounds__(512)
void crf_viterbi_kernel(const float* __restrict__ logits,
                        const float* __restrict__ masks,
                        const float* __restrict__ trans,
                        float* __restrict__ out)
{
    const int n = threadIdx.x & 63;   // next-tag index / lane id
    const int w = threadIdx.x >> 6;   // wave id 0..7, owns prevs [8w, 8w+8)
    const int b = blockIdx.x;
    const int pb = 8 * w;

    __shared__ unsigned bp[128 * 64];   // packed backpointers, 32 KB
    __shared__ int2 pvi[2][8][64];      // double-buffered partials {val bits, idx}
    __shared__ float ys[Tz - 1];        // emitted tags (backtrace)

    // transitions slice: tr[j] = trans[n][8w + j]
    float tr[8];
    {
        const float4* tr4 = reinterpret_cast<const float4*>(trans + n * 64 + pb);
        float4 t0 = tr4[0], t1 = tr4[1];
        tr[0] = t0.x; tr[1] = t0.y; tr[2] = t0.z; tr[3] = t0.w;
        tr[4] = t1.x; tr[5] = t1.y; tr[6] = t1.z; tr[7] = t1.w;
    }

    // fv in registers, lane n = fv[n], replicated per wave
    float fv = (n == 0) ? 0.0f : NEGINF;

    const float* lgbase = logits + (size_t)b * Tz * Sz;
    const float* mkbase = masks + (size_t)b * Tz;

    // depth-4 prefetch: lg_k/mk_k hold data for step i+k
    float lg0 = lgbase[1 * Sz + n], lg1 = lgbase[2 * Sz + n];
    float lg2 = lgbase[3 * Sz + n], lg3 = lgbase[4 * Sz + n];
    float mk0 = mkbase[1], mk1 = mkbase[2], mk2 = mkbase[3], mk3 = mkbase[4];

    unsigned pk = 0;
    float psc = 0.0f;

    #pragma unroll 4
    for (int i = 0; i < Tz - 1; ++i) {
        // gather this wave's fv slice from registers (no LDS, no barrier dep)
        float v0 = rlf(fv, pb + 0) + tr[0];
        float v1 = rlf(fv, pb + 1) + tr[1];
        float v2 = rlf(fv, pb + 2) + tr[2];
        float v3 = rlf(fv, pb + 3) + tr[3];
        float v4 = rlf(fv, pb + 4) + tr[4];
        float v5 = rlf(fv, pb + 5) + tr[5];
        float v6 = rlf(fv, pb + 6) + tr[6];
        float v7 = rlf(fv, pb + 7) + tr[7];

        // exact max (balanced tree) + first-index equality scan
        float m01 = fmaxf(v0, v1), m23 = fmaxf(v2, v3);
        float m45 = fmaxf(v4, v5), m67 = fmaxf(v6, v7);
        float lm  = fmaxf(fmaxf(m01, m23), fmaxf(m45, m67));
        int li = 7;
        li = (v6 == lm) ? 6 : li;
        li = (v5 == lm) ? 5 : li;
        li = (v4 == lm) ? 4 : li;
        li = (v3 == lm) ? 3 : li;
        li = (v2 == lm) ? 2 : li;
        li = (v1 == lm) ? 1 : li;
        li = (v0 == lm) ? 0 : li;

        pvi[i & 1][w][n] = make_int2(__float_as_int(lm), pb + li);
        __syncthreads();                 // the ONLY barrier per step

        // all waves redundantly merge the 8 partials (ordered: q asc = prev asc)
        float cv[8]; int ci[8];
        #pragma unroll
        for (int q = 0; q < 8; ++q) {
            int2 p = pvi[i & 1][q][n];
            cv[q] = __int_as_float(p.x);
            ci[q] = p.y;
        }
        float a01 = fmaxf(cv[0], cv[1]), a23 = fmaxf(cv[2], cv[3]);
        float a45 = fmaxf(cv[4], cv[5]), a67 = fmaxf(cv[6], cv[7]);
        float m   = fmaxf(fmaxf(a01, a23), fmaxf(a45, a67));
        int gi = ci[7];
        #pragma unroll
        for (int q = 6; q >= 0; --q) gi = (cv[q] == m) ? ci[q] : gi;

        if (i == Tz - 2) psc = m;        // vmaxs[-1] pre-feat

        pk |= ((unsigned)gi) << (8 * (i & 3));
        if ((i & 3) == 3) {
            if (w == ((i >> 2) & 7)) bp[(i >> 2) * 64 + n] = pk;
            pk = 0;
        }

        fv = m + lg0 * mk0;              // mask multiplies emission only

        // rotate prefetch (compiler renames under unroll-4)
        lg0 = lg1; lg1 = lg2; lg2 = lg3;
        mk0 = mk1; mk1 = mk2; mk2 = mk3;
        int tnext = (i + 5 < Tz) ? (i + 5) : (Tz - 1);
        lg3 = lgbase[tnext * Sz + n];
        mk3 = mkbase[tnext];
    }

    if (w == 7) {
        bp[127 * 64 + n] = pk;           // flush steps 508..510
        if (n == 63) out[b] = psc;       // path_score = vmaxs[-1][:,63]
    }
    __syncthreads();

    // --- backtrace (wave 0 only; validated readlane chain) ---
    if (w == 0) {
        unsigned wcur = bp[127 * 64 + n];
        int w127_63 = __builtin_amdgcn_readlane((int)wcur, 63);
        int tag = (w127_63 >> 16) & 255; // t0 = bptrs[510][63]

        for (int g = 127; g >= 0; --g) {
            unsigned wnext = (g > 0) ? bp[(g - 1) * 64 + n] : 0u;  // prefetch
            int smax = (g == 127) ? 2 : 3;
            for (int s = smax; s >= 0; --s) {
                int idx = 4 * g + s;
                if (n == 0) ys[idx] = (float)tag;   // emit BEFORE following ptr
                int wd = __builtin_amdgcn_readlane((int)wcur, tag);
                tag = (wd >> (8 * s)) & 255;
            }
            wcur = wnext;
        }
    }
    __syncthreads();

    float* outseq = out + Bz + (size_t)b * (Tz - 1);
    for (int k = threadIdx.x; k < Tz - 1; k += 512) outseq[k] = ys[k];
}

extern "C" void kernel_launch(void* const* d_in, const int* in_sizes, int n_in,
                              void* d_out, int out_size, void* d_ws, size_t ws_size,
                              hipStream_t stream) {
    const float* logits = (const float*)d_in[0];
    const float* masks  = (const float*)d_in[1];
    const float* trans  = (const float*)d_in[2];
    float* out = (float*)d_out;
    (void)in_sizes; (void)n_in; (void)out_size; (void)d_ws; (void)ws_size;

    crf_viterbi_kernel<<<dim3(Bz), dim3(512), 0, stream>>>(logits, masks, trans, out);
}